// Round 12
// baseline (353.442 us; speedup 1.0000x reference)
//
#include <hip/hip_runtime.h>
#include <hip/hip_bf16.h>

#define NEG_SLOPE 0.2f

typedef __attribute__((ext_vector_type(8))) _Float16 half8;  // MFMA A/B frag (4 VGPR)
typedef __attribute__((ext_vector_type(2))) _Float16 h2v;    // packed f16 pair
typedef __attribute__((ext_vector_type(4))) float f32x4;     // MFMA C/D frag

__device__ __forceinline__ float toF(float x) { return x; }
__device__ __forceinline__ float toF(__hip_bfloat16 x) { return __bfloat162float(x); }
__device__ __forceinline__ float toF(_Float16 x) { return (float)x; }

__device__ __forceinline__ void stT(float* p, size_t i, float v) { p[i] = v; }
__device__ __forceinline__ void stT(__hip_bfloat16* p, size_t i, float v) {
    p[i] = __float2bfloat16(v);
}
__device__ __forceinline__ void stT(_Float16* p, size_t i, float v) { p[i] = (_Float16)v; }

template <typename T> struct IsBF { static constexpr bool v = false; };
template <> struct IsBF<__hip_bfloat16> { static constexpr bool v = true; };

// counted vmcnt; each call site folds to one asm after full unroll
__device__ __forceinline__ void vwaitn(int n) {
    if (n == 0) asm volatile("s_waitcnt vmcnt(0)" ::: "memory");
    else if (n == 7) asm volatile("s_waitcnt vmcnt(7)" ::: "memory");
    else if (n == 8) asm volatile("s_waitcnt vmcnt(8)" ::: "memory");
    else if (n == 9) asm volatile("s_waitcnt vmcnt(9)" ::: "memory");
    else asm volatile("s_waitcnt vmcnt(10)" ::: "memory");
}

// wave-local dtype detect from the first 64 words of x (blockDim must be 64)
__device__ __forceinline__ int detect_local(const unsigned* __restrict__ x, int t) {
    unsigned u = x[t];
    int lo_exp = (int)((u >> 7) & 0xFFu);
    int ok = (lo_exp >= 90 && lo_exp <= 141) ? 1 : 0;
    unsigned long long b = __ballot(ok);
    return (__popcll(b) >= 48) ? 1 : 0;
}

// ---------------------------------------------------------------------------
// Weight pre-pack body (bid-parameterized so it can run inside k_prep).
// ---------------------------------------------------------------------------
template <typename WT>
__device__ void packW_body(const WT* W0, const WT* W1, const WT* W2, const WT* b2, int K,
                           _Float16* Bp, float* biasf, int bid) {
    int lane = threadIdx.x;  // 64
    int ksteps = K >> 5;
    int nb = 3 * ksteps * 8;
    if (bid == nb) {
        biasf[lane * 2 + 0] = toF(b2[lane * 2 + 0]);
        biasf[lane * 2 + 1] = toF(b2[lane * 2 + 1]);
        return;
    }
    int ks = bid / 24;
    int rem = bid - ks * 24;
    int o = rem >> 3, ct = rem & 7;
    const WT* W = (o == 0) ? W0 : ((o == 1) ? W1 : W2);
    int c = ct * 16 + (lane & 15);
    int k0 = ks * 32 + (lane >> 4) * 8;
    _Float16* out = Bp + (size_t)bid * 512 + lane * 8;
#pragma unroll
    for (int i = 0; i < 8; ++i) out[i] = (_Float16)toF(W[(size_t)(k0 + i) * 128 + c]);
}

// k_prep: block 0 = write flag + zero gcnt; blocks 1..193 = packW layer0;
// blocks 194..290 = packW layer1. Each block derives flag locally (no race).
__global__ __launch_bounds__(64) void k_prep(const unsigned* __restrict__ x, int* __restrict__ flag,
                                             int* __restrict__ gcnt,
                                             const void* W0a, const void* W1a, const void* W2a,
                                             const void* b2a, const void* W0b, const void* W1b,
                                             const void* W2b, const void* b2b,
                                             _Float16* __restrict__ Bp0, float* __restrict__ bias0,
                                             _Float16* __restrict__ Bp1, float* __restrict__ bias1) {
    typedef __hip_bfloat16 bf;
    int t = threadIdx.x;
    int f = detect_local(x, t);
    int bid = blockIdx.x;
    if (bid == 0) {
        if (t == 0) flag[0] = f;
        gcnt[t] = 0;
        return;
    }
    bid -= 1;
    if (bid < 193) {  // layer 0, K=256 (nb=192, +1 bias)
        if (f == 0)
            packW_body<float>((const float*)W0a, (const float*)W1a, (const float*)W2a,
                              (const float*)b2a, 256, Bp0, bias0, bid);
        else
            packW_body<bf>((const bf*)W0a, (const bf*)W1a, (const bf*)W2a, (const bf*)b2a, 256,
                           Bp0, bias0, bid);
    } else {
        bid -= 193;  // layer 1, K=128 (nb=96, +1 bias)
        if (f == 0)
            packW_body<float>((const float*)W0b, (const float*)W1b, (const float*)W2b,
                              (const float*)b2b, 128, Bp1, bias1, bid);
        else
            packW_body<bf>((const bf*)W0b, (const bf*)W1b, (const bf*)W2b, (const bf*)b2b, 128,
                           Bp1, bias1, bid);
    }
}

// ---------------------------------------------------------------------------
// CSR build — LDS-staged coarse-bucket sort. k_cnt body (smem-carved so it
// can share mega0's dynamic LDS with the gemm blocks).
// ---------------------------------------------------------------------------
__device__ void k_cnt_body(const int* __restrict__ src, const int* __restrict__ dst, int E,
                           int* __restrict__ gcnt, unsigned* __restrict__ bbuf, int cap,
                           int bid, char* smem) {
    int* hist = (int*)smem;          // 64
    int* lbase = hist + 64;          // 64
    int* gbase = lbase + 64;         // 64
    int* lfill = gbase + 64;         // 64
    unsigned* ebuf = (unsigned*)(lfill + 64);      // 4096
    unsigned char* bb = (unsigned char*)(ebuf + 4096);  // 4096
    int t = threadIdx.x;
    int e0 = bid * 4096;
    if (t < 64) { hist[t] = 0; lfill[t] = 0; }
    __syncthreads();
    unsigned my[16];
    int mybkt[16];
#pragma unroll
    for (int i = 0; i < 16; ++i) {
        int idx = e0 + i * 256 + t;
        if (idx < E) {
            int d = dst[idx];
            int b = d >> 10;
            mybkt[i] = b;
            my[i] = (unsigned)src[idx] | ((unsigned)(d & 1023) << 16);
            atomicAdd(&hist[b], 1);
        } else {
            mybkt[i] = -1;
        }
    }
    __syncthreads();
    if (t < 64) {
        int h = hist[t];
        int v = h;
#pragma unroll
        for (int o = 1; o < 64; o <<= 1) {
            int u = __shfl_up(v, o, 64);
            if (t >= o) v += u;
        }
        lbase[t] = v - h;  // exclusive within block
        gbase[t] = (h > 0) ? atomicAdd(&gcnt[t], h) : 0;
    }
    __syncthreads();
#pragma unroll
    for (int i = 0; i < 16; ++i) {
        int b = mybkt[i];
        if (b >= 0) {
            int p = lbase[b] + atomicAdd(&lfill[b], 1);
            ebuf[p] = my[i];
            bb[p] = (unsigned char)b;
        }
    }
    __syncthreads();
    int total = min(4096, E - e0);
    for (int p = t; p < total; p += 256) {
        int b = bb[p];
        int o = gbase[b] + (p - lbase[b]);
        if (o < cap) bbuf[(size_t)b * cap + o] = ebuf[p];
    }
}

// per-bucket: bucket-base scan (inline) + hist + in-LDS scan -> rowptr + place
__global__ __launch_bounds__(256) void k_bhp(const int* __restrict__ gcnt,
                                             const unsigned* __restrict__ bbuf, int cap,
                                             int* __restrict__ rowptr,
                                             int* __restrict__ csr_src, int n, int nb) {
    __shared__ int hist[1024];
    __shared__ int fill[1024];
    __shared__ int wsum[4];
    __shared__ int bbs[64];  // inclusive scan of capped bucket totals
    int b = blockIdx.x, t = threadIdx.x, lane = t & 63, w = t >> 6;
    for (int i = t; i < 1024; i += 256) { hist[i] = 0; fill[i] = 0; }
    if (t < 64) {
        int c = (t < nb) ? min(gcnt[t], cap) : 0;
        int v = c;
#pragma unroll
        for (int o = 1; o < 64; o <<= 1) {
            int u = __shfl_up(v, o, 64);
            if (t >= o) v += u;
        }
        bbs[t] = v;
    }
    __syncthreads();
    int base0 = (b > 0) ? bbs[b - 1] : 0;
    int cnt = min(gcnt[b], cap);
    const unsigned* p = bbuf + (size_t)b * cap;
    for (int i = t; i < cnt; i += 256) atomicAdd(&hist[p[i] >> 16], 1);
    __syncthreads();
    int idx = t * 4;
    int c0 = hist[idx + 0], c1 = hist[idx + 1], c2 = hist[idx + 2], c3 = hist[idx + 3];
    int s1 = c0 + c1, s2 = s1 + c2, s3 = s2 + c3;
    int v = s3;
#pragma unroll
    for (int o = 1; o < 64; o <<= 1) {
        int u = __shfl_up(v, o, 64);
        if (lane >= o) v += u;
    }
    if (lane == 63) wsum[w] = v;
    __syncthreads();
    int woff = 0;
#pragma unroll
    for (int i = 0; i < 3; ++i)
        if (i < w) woff += wsum[i];
    int excl = base0 + woff + v - s3;
    hist[idx + 0] = excl;
    hist[idx + 1] = excl + c0;
    hist[idx + 2] = excl + s1;
    hist[idx + 3] = excl + s2;
    int d0 = b * 1024 + idx;
#pragma unroll
    for (int i = 0; i < 4; ++i)
        if (d0 + i < n) rowptr[d0 + i] = hist[idx + i];
    if (b == nb - 1 && t == 255) rowptr[n] = bbs[nb - 1];
    __syncthreads();
    for (int i = t; i < cnt; i += 256) {
        unsigned e = p[i];
        int dl = (int)(e >> 16);
        int pos = hist[dl] + atomicAdd(&fill[dl], 1);
        csr_src[pos] = (int)(e & 0xFFFFu);
    }
}

// legacy fallback path (N > 65536)
__global__ void k_hist(const int* __restrict__ dst, int E, int* __restrict__ rowptr) {
    int i = blockIdx.x * blockDim.x + threadIdx.x;
    if (i < E) atomicAdd(&rowptr[dst[i] + 1], 1);
}

__global__ void k_scatter(const int* __restrict__ src, const int* __restrict__ dst, int E,
                          const int* __restrict__ rowptr, int* __restrict__ fill,
                          int* __restrict__ csr_src) {
    int i = blockIdx.x * blockDim.x + threadIdx.x;
    if (i < E) {
        int d = dst[i];
        int pos = rowptr[d] + atomicAdd(&fill[d], 1);
        csr_src[pos] = src[i];
    }
}

__global__ __launch_bounds__(256) void k_scan1(int* __restrict__ rowptr,
                                               int* __restrict__ blksum, int n) {
    __shared__ int wsum[4];
    int t = threadIdx.x, lane = t & 63, w = t >> 6;
    int idx = blockIdx.x * 1024 + t * 4;
    int c0 = (idx + 0 < n) ? rowptr[idx + 1] : 0;
    int c1 = (idx + 1 < n) ? rowptr[idx + 2] : 0;
    int c2 = (idx + 2 < n) ? rowptr[idx + 3] : 0;
    int c3 = (idx + 3 < n) ? rowptr[idx + 4] : 0;
    int s1 = c0 + c1, s2 = s1 + c2, s3 = s2 + c3;
    int v = s3;
#pragma unroll
    for (int o = 1; o < 64; o <<= 1) {
        int u = __shfl_up(v, o, 64);
        if (lane >= o) v += u;
    }
    if (lane == 63) wsum[w] = v;
    __syncthreads();
    int woff = 0;
#pragma unroll
    for (int i = 0; i < 3; ++i)
        if (i < w) woff += wsum[i];
    int excl = woff + v - s3;
    if (idx + 0 < n) rowptr[idx + 1] = excl + c0;
    if (idx + 1 < n) rowptr[idx + 2] = excl + s1;
    if (idx + 2 < n) rowptr[idx + 3] = excl + s2;
    if (idx + 3 < n) rowptr[idx + 4] = excl + s3;
    if (t == 255) blksum[blockIdx.x] = woff + v;
}

__global__ void k_scan2(int* __restrict__ blksum, int nblk) {
    int t = threadIdx.x;  // 64
    int v = (t < nblk) ? blksum[t] : 0;
#pragma unroll
    for (int o = 1; o < 64; o <<= 1) {
        int u = __shfl_up(v, o, 64);
        if (t >= o) v += u;
    }
    if (t < nblk) blksum[t] = v;  // inclusive
}

__global__ void k_scan3(int* __restrict__ rowptr, const int* __restrict__ blksum, int n) {
    int idx = blockIdx.x * blockDim.x + threadIdx.x;
    if (idx < n) {
        int b = idx >> 10;
        if (b > 0) rowptr[idx + 1] += blksum[b - 1];
    }
}

// ---------------------------------------------------------------------------
// Fused 3-way MFMA GEMM body — depth-2 A prefetch pipeline (R10 plateau
// ~46us). sB pointer passed in (static or dynamic LDS).
// ---------------------------------------------------------------------------
template <typename AT, typename O2T, int KSTEPS>
__device__ void gemm_body(const AT* __restrict__ A, int N,
                          const _Float16* __restrict__ Bp, const float* __restrict__ biasf,
                          _Float16* __restrict__ O0, _Float16* __restrict__ O1,
                          O2T* __restrict__ O2, _Float16 (*sB)[12288]) {
    const int H = 128;
    const int K = KSTEPS * 32;
    int tid = threadIdx.x;
    int wave = tid >> 6, lane = tid & 63;
    int row0 = (blockIdx.x * 4 + wave) * 16;
    int rr = lane & 15, kg = lane >> 4;
    int arow = min(row0 + rr, N - 1);  // OOB waves still stage + barrier
    constexpr int NR = (sizeof(AT) == 4) ? 2 : 1;

    f32x4 acc[3][8];
#pragma unroll
    for (int o = 0; o < 3; ++o)
#pragma unroll
        for (int ct = 0; ct < 8; ++ct) acc[o][ct] = f32x4{0.f, 0.f, 0.f, 0.f};

    auto stage = [&](int b, int ksv) {
        const char* gsrc = (const char*)(Bp + (size_t)ksv * 12288) + wave * 1024 + lane * 16;
        char* lbase = (char*)(&sB[b][0]) + wave * 1024;
#pragma unroll
        for (int r = 0; r < 6; ++r) {
            __builtin_amdgcn_global_load_lds(
                (const __attribute__((address_space(1))) unsigned*)(gsrc + r * 4096),
                (__attribute__((address_space(3))) unsigned*)(lbase + r * 4096), 16, 0, 0);
        }
    };
    auto loadA = [&](int ksv, uint4* dst) {
        const char* p = (const char*)A + ((size_t)arow * K + ksv * 32 + kg * 8) * sizeof(AT);
        dst[0] = *(const uint4*)p;
        if constexpr (NR == 2) dst[1] = *(const uint4*)(p + 16);
    };
    auto compute = [&](const uint4* raw, const _Float16* sb) {
        half8 a0, a1, r0f, r1f;
        if constexpr (sizeof(AT) == 4) {
            union { uint4 u[2]; float f[8]; } cv;
            cv.u[0] = raw[0]; cv.u[1] = raw[1];
#pragma unroll
            for (int i = 0; i < 8; ++i) {
                float a = cv.f[i];
                _Float16 h = (_Float16)a;
                float lof = a - (float)h;
                _Float16 lo = (_Float16)lof;
                bool pos = a > 0.f;
                a0[i] = h; a1[i] = lo;
                r0f[i] = pos ? h : (_Float16)0.f;
                r1f[i] = pos ? lo : (_Float16)0.f;
            }
        } else if constexpr (IsBF<AT>::v) {
            union { uint4 u4; unsigned u[4]; } cv;
            cv.u4 = raw[0];
#pragma unroll
            for (int q = 0; q < 4; ++q) {
                union { unsigned u; float f; } lo, hi;
                lo.u = cv.u[q] << 16;
                hi.u = cv.u[q] & 0xFFFF0000u;
                a0[2 * q] = (_Float16)lo.f;
                a0[2 * q + 1] = (_Float16)hi.f;
                r0f[2 * q] = (_Float16)fmaxf(lo.f, 0.f);
                r0f[2 * q + 1] = (_Float16)fmaxf(hi.f, 0.f);
            }
        } else {
            union { uint4 u4; half8 h; } cv;
            cv.u4 = raw[0];
            a0 = cv.h;
#pragma unroll
            for (int i = 0; i < 8; ++i)
                r0f[i] = (a0[i] > (_Float16)0.f) ? a0[i] : (_Float16)0.f;
        }
#pragma unroll
        for (int ct = 0; ct < 8; ++ct) {
            half8 w0 = *(const half8*)(sb + (0 * 8 + ct) * 512 + lane * 8);
            half8 w1 = *(const half8*)(sb + (1 * 8 + ct) * 512 + lane * 8);
            half8 w2 = *(const half8*)(sb + (2 * 8 + ct) * 512 + lane * 8);
            acc[0][ct] = __builtin_amdgcn_mfma_f32_16x16x32_f16(a0, w0, acc[0][ct], 0, 0, 0);
            acc[1][ct] = __builtin_amdgcn_mfma_f32_16x16x32_f16(a0, w1, acc[1][ct], 0, 0, 0);
            acc[2][ct] = __builtin_amdgcn_mfma_f32_16x16x32_f16(r0f, w2, acc[2][ct], 0, 0, 0);
            if constexpr (sizeof(AT) == 4) {
                acc[0][ct] = __builtin_amdgcn_mfma_f32_16x16x32_f16(a1, w0, acc[0][ct], 0, 0, 0);
                acc[1][ct] = __builtin_amdgcn_mfma_f32_16x16x32_f16(a1, w1, acc[1][ct], 0, 0, 0);
                acc[2][ct] = __builtin_amdgcn_mfma_f32_16x16x32_f16(r1f, w2, acc[2][ct], 0, 0, 0);
            }
        }
    };

    uint4 rA[3][NR];
    loadA(0, rA[0]);
    loadA(1, rA[1]);
    stage(0, 0);
#pragma unroll
    for (int ks = 0; ks < KSTEPS; ++ks) {
        if (ks + 1 < KSTEPS) {
            stage((ks + 1) & 1, ks + 1);
            asm volatile("" ::: "memory");  // pin: stage(ks+1) issues before loadA(ks+2)
        }
        if (ks + 2 < KSTEPS) loadA(ks + 2, rA[(ks + 2) % 3]);
        if (ks == 0 || ks == KSTEPS - 2) vwaitn(NR + 6);
        else if (ks + 2 < KSTEPS) vwaitn(2 * NR + 6);
        else vwaitn(0);
        __builtin_amdgcn_s_barrier();
        compute(rA[ks % 3], &sB[ks & 1][0]);
        __builtin_amdgcn_s_barrier();
    }

    int rb = row0 + kg * 4;
#pragma unroll
    for (int ct = 0; ct < 8; ++ct) {
        int c = ct * 16 + rr;
        float bv = biasf[c];
#pragma unroll
        for (int j = 0; j < 4; ++j) {
            int row = rb + j;
            if (row < N) {
                size_t o = (size_t)row * H + c;
                O0[o] = (_Float16)acc[0][ct][j];
                O1[o] = (_Float16)acc[1][ct][j];
                stT(O2, o, acc[2][ct][j] + bv);
            }
        }
    }
}

// mega0: blocks [0, ngemm) run layer-0 gemm; blocks [ngemm, ...) run k_cnt.
// 48KB dynamic LDS shared by both block types (gemm keeps 3 blocks/CU).
__global__ __launch_bounds__(256) void mega0(const int* __restrict__ flag, const void* Aext,
                                             int N, int ngemm,
                                             const _Float16* __restrict__ Bp0,
                                             const float* __restrict__ bias0,
                                             _Float16* __restrict__ xs, _Float16* __restrict__ xd,
                                             _Float16* __restrict__ hb,
                                             const int* __restrict__ e_src,
                                             const int* __restrict__ e_dst, int E,
                                             int* __restrict__ gcnt, unsigned* __restrict__ bbuf,
                                             int cap) {
    extern __shared__ char smem[];
    if ((int)blockIdx.x < ngemm) {
        auto sB = (_Float16(*)[12288])smem;
        if (flag[0] == 0)
            gemm_body<float, _Float16, 8>((const float*)Aext, N, Bp0, bias0, xs, xd, hb, sB);
        else
            gemm_body<__hip_bfloat16, _Float16, 8>((const __hip_bfloat16*)Aext, N, Bp0, bias0,
                                                   xs, xd, hb, sB);
    } else {
        k_cnt_body(e_src, e_dst, E, gcnt, bbuf, cap, blockIdx.x - ngemm, smem);
    }
}

// standalone gemm kernels (layer 1 hot path; layer 0 fallback path)
template <int LAYER>
__global__ __launch_bounds__(256) void gemm3_u(const int* __restrict__ flag, const void* Aext,
                                               const _Float16* Af16, int N,
                                               const _Float16* __restrict__ Bp,
                                               const float* __restrict__ biasf,
                                               _Float16* __restrict__ O0,
                                               _Float16* __restrict__ O1, _Float16* O2h,
                                               float* O2f, __hip_bfloat16* O2b) {
    __shared__ _Float16 sB[2][12288];  // 48KB
    int f = flag[0];
    if constexpr (LAYER == 0) {
        if (f == 0)
            gemm_body<float, _Float16, 8>((const float*)Aext, N, Bp, biasf, O0, O1, O2h, sB);
        else
            gemm_body<__hip_bfloat16, _Float16, 8>((const __hip_bfloat16*)Aext, N, Bp, biasf,
                                                   O0, O1, O2h, sB);
    } else {
        if (f == 0)
            gemm_body<_Float16, float, 4>(Af16, N, Bp, biasf, O0, O1, O2f, sB);
        else
            gemm_body<_Float16, __hip_bfloat16, 4>(Af16, N, Bp, biasf, O0, O1, O2b, sB);
    }
}

// ---------------------------------------------------------------------------
// GATv2 edge phase body, H=128: 16 lanes per dst node, 8 edges/iteration
// (R10-measured best: 45.8us; the R11 explicit pipeline regressed — VGPR up,
// occupancy down — and was reverted).
// FINAL=1: fuse the 128->2 final-layer GEMMs into the epilogue.
// ---------------------------------------------------------------------------
template <typename IOT, typename T, int FINAL>
__device__ void gat_body(const _Float16* __restrict__ xs, const _Float16* __restrict__ xd,
                         const int* __restrict__ rowptr, const int* __restrict__ csr_src,
                         IOT* __restrict__ io, const T* __restrict__ att,
                         const T* __restrict__ gbias, int n, int relu_out,
                         const T* __restrict__ Wl, const T* __restrict__ Wr,
                         const T* __restrict__ Wres, const T* __restrict__ bres,
                         float* __restrict__ xsf, float* __restrict__ xdf,
                         float* __restrict__ resf) {
    int tid = threadIdx.x;
    int l = tid & 15;   // feature lane: feats l*8 .. l*8+7
    int g = tid >> 4;   // group (node) in block
    int dst = blockIdx.x * 16 + g;
    if (blockIdx.x * 16 + ((tid >> 6) << 2) >= n) return;  // whole wave OOB
    int dstc = min(dst, n - 1);
    bool act = dst < n;

    union U4H { uint4 u; h2v h[4]; };
    U4H du; du.u = *(const uint4*)(xd + (size_t)dstc * 128 + l * 8);
    h2v ap[4];
#pragma unroll
    for (int c = 0; c < 4; ++c) {
        ap[c][0] = (_Float16)toF(att[l * 8 + 2 * c]);
        ap[c][1] = (_Float16)toF(att[l * 8 + 2 * c + 1]);
    }
    const _Float16 ks = (_Float16)NEG_SLOPE;
    const h2v k02 = {ks, ks};

    int beg = rowptr[dstc];
    int end = act ? rowptr[dstc + 1] : beg;
    float m = -INFINITY, s = 0.f;
    h2v acc[4];
#pragma unroll
    for (int c = 0; c < 4; ++c) acc[c] = h2v{(_Float16)0.f, (_Float16)0.f};

    for (int j = beg; j < end; j += 8) {
        int rem = end - j;
        U4H v[8];
#pragma unroll
        for (int q = 0; q < 8; ++q) {
            int idx = j + ((rem > q) ? q : 0);
            int sq = csr_src[idx];
            v[q].u = *(const uint4*)(xs + (size_t)sq * 128 + l * 8);
        }
        float p[8];
#pragma unroll
        for (int q = 0; q < 8; ++q) p[q] = 0.f;
#pragma unroll
        for (int c = 0; c < 4; ++c) {
#pragma unroll
            for (int q = 0; q < 8; ++q) {
                h2v t = v[q].h[c] + du.h[c];
                t = __builtin_elementwise_max(t, t * k02);  // leaky: max(h, 0.2h)
                p[q] = __builtin_amdgcn_fdot2(t, ap[c], p[q], false);
            }
        }
#pragma unroll
        for (int o = 1; o < 16; o <<= 1) {
#pragma unroll
            for (int q = 0; q < 8; ++q) p[q] += __shfl_xor(p[q], o, 16);
        }
#pragma unroll
        for (int q = 1; q < 8; ++q)
            if (rem < q + 1) p[q] = -INFINITY;
        float pm = p[0];
#pragma unroll
        for (int q = 1; q < 8; ++q) pm = fmaxf(pm, p[q]);
        float nm = fmaxf(m, pm);
        float sc = __expf(m - nm);  // first iter: exp(-inf)=0
        float w[8];
        float ws = 0.f;
#pragma unroll
        for (int q = 0; q < 8; ++q) {
            w[q] = __expf(p[q] - nm);
            ws += w[q];
        }
        s = s * sc + ws;
        _Float16 sch = (_Float16)sc;
        h2v scp = {sch, sch};
        h2v wp[8];
#pragma unroll
        for (int q = 0; q < 8; ++q) {
            _Float16 wh = (_Float16)w[q];
            wp[q] = h2v{wh, wh};
        }
#pragma unroll
        for (int c = 0; c < 4; ++c) {
            h2v a = acc[c] * scp;
#pragma unroll
            for (int q = 0; q < 8; ++q) a = a + v[q].h[c] * wp[q];
            acc[c] = a;
        }
        m = nm;
    }

    if (act) {
        float r = 1.f / (s + 1e-16f);
        size_t base = (size_t)dst * 128 + l * 8;
        float ev[8];
#pragma unroll
        for (int c = 0; c < 4; ++c) {
            int f0 = l * 8 + 2 * c;
            float v0 = (float)acc[c][0] * r + toF(gbias[f0]) + toF(io[base + 2 * c]);
            float v1 = (float)acc[c][1] * r + toF(gbias[f0 + 1]) + toF(io[base + 2 * c + 1]);
            if (relu_out) { v0 = fmaxf(v0, 0.f); v1 = fmaxf(v1, 0.f); }
            stT(io, base + 2 * c, v0);
            stT(io, base + 2 * c + 1, v1);
            ev[2 * c] = v0;
            ev[2 * c + 1] = v1;
        }
        if constexpr (FINAL) {
            float d[6] = {0.f, 0.f, 0.f, 0.f, 0.f, 0.f};
#pragma unroll
            for (int f = 0; f < 8; ++f) {
                int fg = (l * 8 + f) * 2;
                float e = ev[f];
                float rp = fmaxf(e, 0.f);
                d[0] += e * toF(Wl[fg]);
                d[1] += e * toF(Wl[fg + 1]);
                d[2] += e * toF(Wr[fg]);
                d[3] += e * toF(Wr[fg + 1]);
                d[4] += rp * toF(Wres[fg]);
                d[5] += rp * toF(Wres[fg + 1]);
            }
#pragma unroll
            for (int i = 0; i < 6; ++i) {
#pragma unroll
                for (int o = 1; o < 16; o <<= 1) d[i] += __shfl_xor(d[i], o, 16);
            }
            if (l == 0) {
                xsf[dst * 2 + 0] = d[0];
                xsf[dst * 2 + 1] = d[1];
                xdf[dst * 2 + 0] = d[2];
                xdf[dst * 2 + 1] = d[3];
                resf[dst * 2 + 0] = d[4] + toF(bres[0]);
                resf[dst * 2 + 1] = d[5] + toF(bres[1]);
            }
        }
    }
}

// unified gat kernel: FINAL=0 (io = hb f16), FINAL=1 (io = embF/embB by flag,
// fused final-layer 128->2 GEMMs).
template <int FINAL>
__global__ __launch_bounds__(256) void gat_u(const int* __restrict__ flag,
                                             const _Float16* __restrict__ xs,
                                             const _Float16* __restrict__ xd,
                                             const int* __restrict__ rowptr,
                                             const int* __restrict__ csr_src, _Float16* io_h,
                                             float* io_f, __hip_bfloat16* io_b, const void* att,
                                             const void* gbias, int n, int relu_out,
                                             const void* Wl, const void* Wr, const void* Wres,
                                             const void* bres, float* xsf, float* xdf,
                                             float* resf) {
    typedef __hip_bfloat16 bf;
    int f = flag[0];
    if constexpr (FINAL == 0) {
        if (f == 0)
            gat_body<_Float16, float, 0>(xs, xd, rowptr, csr_src, io_h, (const float*)att,
                                         (const float*)gbias, n, relu_out, nullptr, nullptr,
                                         nullptr, nullptr, nullptr, nullptr, nullptr);
        else
            gat_body<_Float16, bf, 0>(xs, xd, rowptr, csr_src, io_h, (const bf*)att,
                                      (const bf*)gbias, n, relu_out, nullptr, nullptr, nullptr,
                                      nullptr, nullptr, nullptr, nullptr);
    } else {
        if (f == 0)
            gat_body<float, float, 1>(xs, xd, rowptr, csr_src, io_f, (const float*)att,
                                      (const float*)gbias, n, relu_out, (const float*)Wl,
                                      (const float*)Wr, (const float*)Wres, (const float*)bres,
                                      xsf, xdf, resf);
        else
            gat_body<bf, bf, 1>(xs, xd, rowptr, csr_src, io_b, (const bf*)att, (const bf*)gbias,
                                n, relu_out, (const bf*)Wl, (const bf*)Wr, (const bf*)Wres,
                                (const bf*)bres, xsf, xdf, resf);
    }
}

// ---------------------------------------------------------------------------
// Final edge phase (OUT=2): one thread per dst node, 4-way unrolled online
// softmax.
// ---------------------------------------------------------------------------
template <typename T>
__device__ void fe_body(const float* __restrict__ xsf, const float* __restrict__ xdf,
                        const float* __restrict__ resf, const int* __restrict__ rowptr,
                        const int* __restrict__ csr_src, const T* __restrict__ att,
                        const T* __restrict__ gb, T* __restrict__ out, int n) {
    int dst = blockIdx.x * blockDim.x + threadIdx.x;
    if (dst >= n) return;
    float2 dv = ((const float2*)xdf)[dst];
    float a0 = toF(att[0]), a1 = toF(att[1]);
    float m = -INFINITY, s = 0.f, acc0 = 0.f, acc1 = 0.f;
    int beg = rowptr[dst], end = rowptr[dst + 1];
    for (int j = beg; j < end; j += 4) {
        int rem = end - j;
        int i1 = (rem > 1) ? 1 : 0, i2 = (rem > 2) ? 2 : 0, i3 = (rem > 3) ? 3 : 0;
        int s0 = csr_src[j];
        int s1 = csr_src[j + i1];
        int s2 = csr_src[j + i2];
        int s3 = csr_src[j + i3];
        float2 v0 = ((const float2*)xsf)[s0];
        float2 v1 = ((const float2*)xsf)[s1];
        float2 v2 = ((const float2*)xsf)[s2];
        float2 v3 = ((const float2*)xsf)[s3];
        float h0, h1, e0, e1, e2, e3;
        h0 = v0.x + dv.x; h0 = fmaxf(h0, NEG_SLOPE * h0);
        h1 = v0.y + dv.y; h1 = fmaxf(h1, NEG_SLOPE * h1);
        e0 = h0 * a0 + h1 * a1;
        h0 = v1.x + dv.x; h0 = fmaxf(h0, NEG_SLOPE * h0);
        h1 = v1.y + dv.y; h1 = fmaxf(h1, NEG_SLOPE * h1);
        e1 = h0 * a0 + h1 * a1;
        h0 = v2.x + dv.x; h0 = fmaxf(h0, NEG_SLOPE * h0);
        h1 = v2.y + dv.y; h1 = fmaxf(h1, NEG_SLOPE * h1);
        e2 = h0 * a0 + h1 * a1;
        h0 = v3.x + dv.x; h0 = fmaxf(h0, NEG_SLOPE * h0);
        h1 = v3.y + dv.y; h1 = fmaxf(h1, NEG_SLOPE * h1);
        e3 = h0 * a0 + h1 * a1;
        if (rem < 2) e1 = -INFINITY;
        if (rem < 3) e2 = -INFINITY;
        if (rem < 4) e3 = -INFINITY;
        float pm = fmaxf(fmaxf(e0, e1), fmaxf(e2, e3));
        float nm = fmaxf(m, pm);
        float sc = __expf(m - nm);
        float w0 = __expf(e0 - nm), w1 = __expf(e1 - nm);
        float w2 = __expf(e2 - nm), w3 = __expf(e3 - nm);
        s = s * sc + ((w0 + w1) + (w2 + w3));
        acc0 = acc0 * sc + ((w0 * v0.x + w1 * v1.x) + (w2 * v2.x + w3 * v3.x));
        acc1 = acc1 * sc + ((w0 * v0.y + w1 * v1.y) + (w2 * v2.y + w3 * v3.y));
        m = nm;
    }
    float r = 1.f / (s + 1e-16f);
    float2 rv = ((const float2*)resf)[dst];
    stT(out, (size_t)dst * 2 + 0, acc0 * r + toF(gb[0]) + rv.x);
    stT(out, (size_t)dst * 2 + 1, acc1 * r + toF(gb[1]) + rv.y);
}

__global__ void final_edge_u(const int* __restrict__ flag, const float* __restrict__ xsf,
                             const float* __restrict__ xdf, const float* __restrict__ resf,
                             const int* __restrict__ rowptr, const int* __restrict__ csr_src,
                             const void* att, const void* gb, void* out, int n) {
    typedef __hip_bfloat16 bf;
    if (flag[0] == 0)
        fe_body<float>(xsf, xdf, resf, rowptr, csr_src, (const float*)att, (const float*)gb,
                       (float*)out, n);
    else
        fe_body<bf>(xsf, xdf, resf, rowptr, csr_src, (const bf*)att, (const bf*)gb, (bf*)out, n);
}

// ---------------------------------------------------------------------------
extern "C" void kernel_launch(void* const* d_in, const int* in_sizes, int n_in,
                              void* d_out, int out_size, void* d_ws, size_t ws_size,
                              hipStream_t stream) {
    typedef __hip_bfloat16 bf;
    typedef _Float16 f16;
    const int IN = 256, H = 128;
    const int N = in_sizes[0] / IN;  // 50000
    const int E = in_sizes[1] / 2;   // 800000

    const int* ei = (const int*)d_in[1];

    size_t off = 0;
    auto alloc = [&](size_t bytes) {
        void* p = (char*)d_ws + off;
        off += (bytes + 255) & ~(size_t)255;
        return p;
    };
    f16* xs = (f16*)alloc((size_t)N * H * 2);
    f16* xd = (f16*)alloc((size_t)N * H * 2);
    f16* hb = (f16*)alloc((size_t)N * H * 2);
    int* flag = (int*)alloc(256);
    int* rowptr = (int*)alloc((size_t)(N + 1) * 4);
    int* fill = (int*)alloc((size_t)N * 4);
    int* blksum = (int*)alloc(256 * 4);
    int* csr_src = (int*)alloc((size_t)E * 4);
    float* xsf = (float*)alloc((size_t)N * 2 * 4);
    float* xdf = (float*)alloc((size_t)N * 2 * 4);
    float* resf = (float*)alloc((size_t)N * 2 * 4);
    f16* Bp0 = (f16*)alloc((size_t)3 * 8 * 8 * 512 * 2);  // 192 KB, ks-major
    f16* Bp1 = (f16*)alloc((size_t)3 * 4 * 8 * 512 * 2);  // 96 KB
    float* bias0 = (float*)alloc(128 * 4);
    float* bias1 = (float*)alloc(128 * 4);
    // bucketed CSR build buffers (coarse buckets of 1024 dst nodes)
    const int NB = (N + 1023) / 1024;              // <= 64 when N <= 65536
    const int CAP = ((2 * (E / (NB > 0 ? NB : 1) + 1) + 255) / 256) * 256;  // 2x mean
    int* gcnt = (int*)alloc(64 * 4);
    unsigned* bbuf = (unsigned*)alloc((size_t)NB * CAP * 4);

    const int* e_src = ei;
    const int* e_dst = ei + E;

    // ---- prep: detect + zero gcnt + pack both weight sets (1 launch) ----
    k_prep<<<1 + 193 + 97, 64, 0, stream>>>((const unsigned*)d_in[0], flag, gcnt,
                                            d_in[2], d_in[3], d_in[14], d_in[15],
                                            d_in[6], d_in[7], d_in[16], d_in[17],
                                            Bp0, bias0, Bp1, bias1);

    const int g64 = (N + 63) / 64;     // MFMA gemm grid: 64 rows/block
    const int eblk16 = (N + 15) / 16;  // gat grid: 16 nodes/block
    const int ncnt = (E + 4095) / 4096;

    float* embF = (float*)d_out + (size_t)N * 2;
    bf* embB = (bf*)d_out + (size_t)N * 2;

    if (N <= 65536) {
        // ---- mega0: layer-0 gemm || edge binning (independent; one grid) ----
        mega0<<<g64 + ncnt, 256, 49152, stream>>>(flag, d_in[0], N, g64, Bp0, bias0, xs, xd,
                                                  hb, e_src, e_dst, E, gcnt, bbuf, CAP);
        k_bhp<<<NB, 256, 0, stream>>>(gcnt, bbuf, CAP, rowptr, csr_src, N, NB);
    } else {  // legacy fallback
        const int nblk = (N + 1023) / 1024;
        hipMemsetAsync(rowptr, 0, (size_t)(N + 1) * 4, stream);
        hipMemsetAsync(fill, 0, (size_t)N * 4, stream);
        k_hist<<<(E + 255) / 256, 256, 0, stream>>>(e_dst, E, rowptr);
        k_scan1<<<nblk, 256, 0, stream>>>(rowptr, blksum, N);
        k_scan2<<<1, 64, 0, stream>>>(blksum, nblk);
        k_scan3<<<(N + 255) / 256, 256, 0, stream>>>(rowptr, blksum, N);
        k_scatter<<<(E + 255) / 256, 256, 0, stream>>>(e_src, e_dst, E, rowptr, fill, csr_src);
        gemm3_u<0><<<g64, 256, 0, stream>>>(flag, d_in[0], nullptr, N, Bp0, bias0, xs, xd, hb,
                                            nullptr, nullptr);
    }

    // ---- layer 0 edge phase: xs/xd -> hb (+relu, +residual) ----
    gat_u<0><<<eblk16, 256, 0, stream>>>(flag, xs, xd, rowptr, csr_src, hb, nullptr, nullptr,
                                         d_in[4], d_in[5], N, 1, nullptr, nullptr, nullptr,
                                         nullptr, nullptr, nullptr, nullptr);

    // ---- layer 1: hb[N,128] -> emb in d_out + fused final-layer GEMMs ----
    gemm3_u<1><<<g64, 256, 0, stream>>>(flag, nullptr, hb, N, Bp1, bias1, xs, xd, nullptr,
                                        embF, embB);
    gat_u<1><<<eblk16, 256, 0, stream>>>(flag, xs, xd, rowptr, csr_src, nullptr, embF, embB,
                                         d_in[8], d_in[9], N, 0, d_in[10], d_in[11], d_in[18],
                                         d_in[19], xsf, xdf, resf);

    // ---- final edge phase: xsf/xdf/resf -> out [N,2] ----
    final_edge_u<<<(N + 255) / 256, 256, 0, stream>>>(flag, xsf, xdf, resf, rowptr, csr_src,
                                                      d_in[12], d_in[13], d_out, N);
}

// Round 13
// 316.683 us; speedup vs baseline: 1.1161x; 1.1161x over previous
//
#include <hip/hip_runtime.h>
#include <hip/hip_bf16.h>

#define NEG_SLOPE 0.2f

typedef __attribute__((ext_vector_type(8))) _Float16 half8;  // MFMA A/B frag (4 VGPR)
typedef __attribute__((ext_vector_type(2))) _Float16 h2v;    // packed f16 pair
typedef __attribute__((ext_vector_type(4))) float f32x4;     // MFMA C/D frag

__device__ __forceinline__ float toF(float x) { return x; }
__device__ __forceinline__ float toF(__hip_bfloat16 x) { return __bfloat162float(x); }
__device__ __forceinline__ float toF(_Float16 x) { return (float)x; }

__device__ __forceinline__ void stT(float* p, size_t i, float v) { p[i] = v; }
__device__ __forceinline__ void stT(__hip_bfloat16* p, size_t i, float v) {
    p[i] = __float2bfloat16(v);
}
__device__ __forceinline__ void stT(_Float16* p, size_t i, float v) { p[i] = (_Float16)v; }

template <typename T> struct IsBF { static constexpr bool v = false; };
template <> struct IsBF<__hip_bfloat16> { static constexpr bool v = true; };

// counted vmcnt; each call site folds to one asm after full unroll
__device__ __forceinline__ void vwaitn(int n) {
    if (n == 0) asm volatile("s_waitcnt vmcnt(0)" ::: "memory");
    else if (n == 7) asm volatile("s_waitcnt vmcnt(7)" ::: "memory");
    else if (n == 8) asm volatile("s_waitcnt vmcnt(8)" ::: "memory");
    else if (n == 9) asm volatile("s_waitcnt vmcnt(9)" ::: "memory");
    else asm volatile("s_waitcnt vmcnt(10)" ::: "memory");
}

// wave-local dtype detect from the first 64 words of x (blockDim must be 64)
__device__ __forceinline__ int detect_local(const unsigned* __restrict__ x, int t) {
    unsigned u = x[t];
    int lo_exp = (int)((u >> 7) & 0xFFu);
    int ok = (lo_exp >= 90 && lo_exp <= 141) ? 1 : 0;
    unsigned long long b = __ballot(ok);
    return (__popcll(b) >= 48) ? 1 : 0;
}

// ---------------------------------------------------------------------------
// Weight pre-pack body (bid-parameterized so it can run inside k_prep).
// ---------------------------------------------------------------------------
template <typename WT>
__device__ void packW_body(const WT* W0, const WT* W1, const WT* W2, const WT* b2, int K,
                           _Float16* Bp, float* biasf, int bid) {
    int lane = threadIdx.x;  // 64
    int ksteps = K >> 5;
    int nb = 3 * ksteps * 8;
    if (bid == nb) {
        biasf[lane * 2 + 0] = toF(b2[lane * 2 + 0]);
        biasf[lane * 2 + 1] = toF(b2[lane * 2 + 1]);
        return;
    }
    int ks = bid / 24;
    int rem = bid - ks * 24;
    int o = rem >> 3, ct = rem & 7;
    const WT* W = (o == 0) ? W0 : ((o == 1) ? W1 : W2);
    int c = ct * 16 + (lane & 15);
    int k0 = ks * 32 + (lane >> 4) * 8;
    _Float16* out = Bp + (size_t)bid * 512 + lane * 8;
#pragma unroll
    for (int i = 0; i < 8; ++i) out[i] = (_Float16)toF(W[(size_t)(k0 + i) * 128 + c]);
}

// k_prep: block 0 = write flag + zero gcnt; blocks 1..193 = packW layer0;
// blocks 194..290 = packW layer1. Each block derives flag locally (no race).
__global__ __launch_bounds__(64) void k_prep(const unsigned* __restrict__ x, int* __restrict__ flag,
                                             int* __restrict__ gcnt,
                                             const void* W0a, const void* W1a, const void* W2a,
                                             const void* b2a, const void* W0b, const void* W1b,
                                             const void* W2b, const void* b2b,
                                             _Float16* __restrict__ Bp0, float* __restrict__ bias0,
                                             _Float16* __restrict__ Bp1, float* __restrict__ bias1) {
    typedef __hip_bfloat16 bf;
    int t = threadIdx.x;
    int f = detect_local(x, t);
    int bid = blockIdx.x;
    if (bid == 0) {
        if (t == 0) flag[0] = f;
        gcnt[t] = 0;
        return;
    }
    bid -= 1;
    if (bid < 193) {  // layer 0, K=256 (nb=192, +1 bias)
        if (f == 0)
            packW_body<float>((const float*)W0a, (const float*)W1a, (const float*)W2a,
                              (const float*)b2a, 256, Bp0, bias0, bid);
        else
            packW_body<bf>((const bf*)W0a, (const bf*)W1a, (const bf*)W2a, (const bf*)b2a, 256,
                           Bp0, bias0, bid);
    } else {
        bid -= 193;  // layer 1, K=128 (nb=96, +1 bias)
        if (f == 0)
            packW_body<float>((const float*)W0b, (const float*)W1b, (const float*)W2b,
                              (const float*)b2b, 128, Bp1, bias1, bid);
        else
            packW_body<bf>((const bf*)W0b, (const bf*)W1b, (const bf*)W2b, (const bf*)b2b, 128,
                           Bp1, bias1, bid);
    }
}

// ---------------------------------------------------------------------------
// CSR build — LDS-staged coarse-bucket sort (standalone kernel, static LDS:
// own compact register budget; the R12 mega-fusion pushed the co-compiled
// gemm path to 196 VGPR and was reverted).
// ---------------------------------------------------------------------------
__global__ __launch_bounds__(256) void k_cnt(const int* __restrict__ src,
                                             const int* __restrict__ dst, int E,
                                             int* __restrict__ gcnt,
                                             unsigned* __restrict__ bbuf, int cap) {
    __shared__ int hist[64];
    __shared__ int lbase[64];
    __shared__ int gbase[64];
    __shared__ int lfill[64];
    __shared__ unsigned ebuf[4096];
    __shared__ unsigned char bb[4096];
    int t = threadIdx.x;
    int e0 = blockIdx.x * 4096;
    if (t < 64) { hist[t] = 0; lfill[t] = 0; }
    __syncthreads();
    unsigned my[16];
    int mybkt[16];
#pragma unroll
    for (int i = 0; i < 16; ++i) {
        int idx = e0 + i * 256 + t;
        if (idx < E) {
            int d = dst[idx];
            int b = d >> 10;
            mybkt[i] = b;
            my[i] = (unsigned)src[idx] | ((unsigned)(d & 1023) << 16);
            atomicAdd(&hist[b], 1);
        } else {
            mybkt[i] = -1;
        }
    }
    __syncthreads();
    if (t < 64) {
        int h = hist[t];
        int v = h;
#pragma unroll
        for (int o = 1; o < 64; o <<= 1) {
            int u = __shfl_up(v, o, 64);
            if (t >= o) v += u;
        }
        lbase[t] = v - h;  // exclusive within block
        gbase[t] = (h > 0) ? atomicAdd(&gcnt[t], h) : 0;
    }
    __syncthreads();
#pragma unroll
    for (int i = 0; i < 16; ++i) {
        int b = mybkt[i];
        if (b >= 0) {
            int p = lbase[b] + atomicAdd(&lfill[b], 1);
            ebuf[p] = my[i];
            bb[p] = (unsigned char)b;
        }
    }
    __syncthreads();
    int total = min(4096, E - e0);
    for (int p = t; p < total; p += 256) {
        int b = bb[p];
        int o = gbase[b] + (p - lbase[b]);
        if (o < cap) bbuf[(size_t)b * cap + o] = ebuf[p];
    }
}

// per-bucket: bucket-base scan (inline) + hist + in-LDS scan -> rowptr + place
__global__ __launch_bounds__(256) void k_bhp(const int* __restrict__ gcnt,
                                             const unsigned* __restrict__ bbuf, int cap,
                                             int* __restrict__ rowptr,
                                             int* __restrict__ csr_src, int n, int nb) {
    __shared__ int hist[1024];
    __shared__ int fill[1024];
    __shared__ int wsum[4];
    __shared__ int bbs[64];  // inclusive scan of capped bucket totals
    int b = blockIdx.x, t = threadIdx.x, lane = t & 63, w = t >> 6;
    for (int i = t; i < 1024; i += 256) { hist[i] = 0; fill[i] = 0; }
    if (t < 64) {
        int c = (t < nb) ? min(gcnt[t], cap) : 0;
        int v = c;
#pragma unroll
        for (int o = 1; o < 64; o <<= 1) {
            int u = __shfl_up(v, o, 64);
            if (t >= o) v += u;
        }
        bbs[t] = v;
    }
    __syncthreads();
    int base0 = (b > 0) ? bbs[b - 1] : 0;
    int cnt = min(gcnt[b], cap);
    const unsigned* p = bbuf + (size_t)b * cap;
    for (int i = t; i < cnt; i += 256) atomicAdd(&hist[p[i] >> 16], 1);
    __syncthreads();
    int idx = t * 4;
    int c0 = hist[idx + 0], c1 = hist[idx + 1], c2 = hist[idx + 2], c3 = hist[idx + 3];
    int s1 = c0 + c1, s2 = s1 + c2, s3 = s2 + c3;
    int v = s3;
#pragma unroll
    for (int o = 1; o < 64; o <<= 1) {
        int u = __shfl_up(v, o, 64);
        if (lane >= o) v += u;
    }
    if (lane == 63) wsum[w] = v;
    __syncthreads();
    int woff = 0;
#pragma unroll
    for (int i = 0; i < 3; ++i)
        if (i < w) woff += wsum[i];
    int excl = base0 + woff + v - s3;
    hist[idx + 0] = excl;
    hist[idx + 1] = excl + c0;
    hist[idx + 2] = excl + s1;
    hist[idx + 3] = excl + s2;
    int d0 = b * 1024 + idx;
#pragma unroll
    for (int i = 0; i < 4; ++i)
        if (d0 + i < n) rowptr[d0 + i] = hist[idx + i];
    if (b == nb - 1 && t == 255) rowptr[n] = bbs[nb - 1];
    __syncthreads();
    for (int i = t; i < cnt; i += 256) {
        unsigned e = p[i];
        int dl = (int)(e >> 16);
        int pos = hist[dl] + atomicAdd(&fill[dl], 1);
        csr_src[pos] = (int)(e & 0xFFFFu);
    }
}

// legacy fallback path (N > 65536)
__global__ void k_hist(const int* __restrict__ dst, int E, int* __restrict__ rowptr) {
    int i = blockIdx.x * blockDim.x + threadIdx.x;
    if (i < E) atomicAdd(&rowptr[dst[i] + 1], 1);
}

__global__ void k_scatter(const int* __restrict__ src, const int* __restrict__ dst, int E,
                          const int* __restrict__ rowptr, int* __restrict__ fill,
                          int* __restrict__ csr_src) {
    int i = blockIdx.x * blockDim.x + threadIdx.x;
    if (i < E) {
        int d = dst[i];
        int pos = rowptr[d] + atomicAdd(&fill[d], 1);
        csr_src[pos] = src[i];
    }
}

__global__ __launch_bounds__(256) void k_scan1(int* __restrict__ rowptr,
                                               int* __restrict__ blksum, int n) {
    __shared__ int wsum[4];
    int t = threadIdx.x, lane = t & 63, w = t >> 6;
    int idx = blockIdx.x * 1024 + t * 4;
    int c0 = (idx + 0 < n) ? rowptr[idx + 1] : 0;
    int c1 = (idx + 1 < n) ? rowptr[idx + 2] : 0;
    int c2 = (idx + 2 < n) ? rowptr[idx + 3] : 0;
    int c3 = (idx + 3 < n) ? rowptr[idx + 4] : 0;
    int s1 = c0 + c1, s2 = s1 + c2, s3 = s2 + c3;
    int v = s3;
#pragma unroll
    for (int o = 1; o < 64; o <<= 1) {
        int u = __shfl_up(v, o, 64);
        if (lane >= o) v += u;
    }
    if (lane == 63) wsum[w] = v;
    __syncthreads();
    int woff = 0;
#pragma unroll
    for (int i = 0; i < 3; ++i)
        if (i < w) woff += wsum[i];
    int excl = woff + v - s3;
    if (idx + 0 < n) rowptr[idx + 1] = excl + c0;
    if (idx + 1 < n) rowptr[idx + 2] = excl + s1;
    if (idx + 2 < n) rowptr[idx + 3] = excl + s2;
    if (idx + 3 < n) rowptr[idx + 4] = excl + s3;
    if (t == 255) blksum[blockIdx.x] = woff + v;
}

__global__ void k_scan2(int* __restrict__ blksum, int nblk) {
    int t = threadIdx.x;  // 64
    int v = (t < nblk) ? blksum[t] : 0;
#pragma unroll
    for (int o = 1; o < 64; o <<= 1) {
        int u = __shfl_up(v, o, 64);
        if (t >= o) v += u;
    }
    if (t < nblk) blksum[t] = v;  // inclusive
}

__global__ void k_scan3(int* __restrict__ rowptr, const int* __restrict__ blksum, int n) {
    int idx = blockIdx.x * blockDim.x + threadIdx.x;
    if (idx < n) {
        int b = idx >> 10;
        if (b > 0) rowptr[idx + 1] += blksum[b - 1];
    }
}

// ---------------------------------------------------------------------------
// Fused 3-way MFMA GEMM body — depth-2 A prefetch pipeline (measured ~46us,
// 112 VGPR, 3 blocks/CU with static 48KB LDS).
// ---------------------------------------------------------------------------
template <typename AT, typename O2T, int KSTEPS>
__device__ void gemm_body(const AT* __restrict__ A, int N,
                          const _Float16* __restrict__ Bp, const float* __restrict__ biasf,
                          _Float16* __restrict__ O0, _Float16* __restrict__ O1,
                          O2T* __restrict__ O2, _Float16 (*sB)[12288]) {
    const int H = 128;
    const int K = KSTEPS * 32;
    int tid = threadIdx.x;
    int wave = tid >> 6, lane = tid & 63;
    int row0 = (blockIdx.x * 4 + wave) * 16;
    int rr = lane & 15, kg = lane >> 4;
    int arow = min(row0 + rr, N - 1);  // OOB waves still stage + barrier
    constexpr int NR = (sizeof(AT) == 4) ? 2 : 1;

    f32x4 acc[3][8];
#pragma unroll
    for (int o = 0; o < 3; ++o)
#pragma unroll
        for (int ct = 0; ct < 8; ++ct) acc[o][ct] = f32x4{0.f, 0.f, 0.f, 0.f};

    auto stage = [&](int b, int ksv) {
        const char* gsrc = (const char*)(Bp + (size_t)ksv * 12288) + wave * 1024 + lane * 16;
        char* lbase = (char*)(&sB[b][0]) + wave * 1024;
#pragma unroll
        for (int r = 0; r < 6; ++r) {
            __builtin_amdgcn_global_load_lds(
                (const __attribute__((address_space(1))) unsigned*)(gsrc + r * 4096),
                (__attribute__((address_space(3))) unsigned*)(lbase + r * 4096), 16, 0, 0);
        }
    };
    auto loadA = [&](int ksv, uint4* dst) {
        const char* p = (const char*)A + ((size_t)arow * K + ksv * 32 + kg * 8) * sizeof(AT);
        dst[0] = *(const uint4*)p;
        if constexpr (NR == 2) dst[1] = *(const uint4*)(p + 16);
    };
    auto compute = [&](const uint4* raw, const _Float16* sb) {
        half8 a0, a1, r0f, r1f;
        if constexpr (sizeof(AT) == 4) {
            union { uint4 u[2]; float f[8]; } cv;
            cv.u[0] = raw[0]; cv.u[1] = raw[1];
#pragma unroll
            for (int i = 0; i < 8; ++i) {
                float a = cv.f[i];
                _Float16 h = (_Float16)a;
                float lof = a - (float)h;
                _Float16 lo = (_Float16)lof;
                bool pos = a > 0.f;
                a0[i] = h; a1[i] = lo;
                r0f[i] = pos ? h : (_Float16)0.f;
                r1f[i] = pos ? lo : (_Float16)0.f;
            }
        } else if constexpr (IsBF<AT>::v) {
            union { uint4 u4; unsigned u[4]; } cv;
            cv.u4 = raw[0];
#pragma unroll
            for (int q = 0; q < 4; ++q) {
                union { unsigned u; float f; } lo, hi;
                lo.u = cv.u[q] << 16;
                hi.u = cv.u[q] & 0xFFFF0000u;
                a0[2 * q] = (_Float16)lo.f;
                a0[2 * q + 1] = (_Float16)hi.f;
                r0f[2 * q] = (_Float16)fmaxf(lo.f, 0.f);
                r0f[2 * q + 1] = (_Float16)fmaxf(hi.f, 0.f);
            }
        } else {
            union { uint4 u4; half8 h; } cv;
            cv.u4 = raw[0];
            a0 = cv.h;
#pragma unroll
            for (int i = 0; i < 8; ++i)
                r0f[i] = (a0[i] > (_Float16)0.f) ? a0[i] : (_Float16)0.f;
        }
#pragma unroll
        for (int ct = 0; ct < 8; ++ct) {
            half8 w0 = *(const half8*)(sb + (0 * 8 + ct) * 512 + lane * 8);
            half8 w1 = *(const half8*)(sb + (1 * 8 + ct) * 512 + lane * 8);
            half8 w2 = *(const half8*)(sb + (2 * 8 + ct) * 512 + lane * 8);
            acc[0][ct] = __builtin_amdgcn_mfma_f32_16x16x32_f16(a0, w0, acc[0][ct], 0, 0, 0);
            acc[1][ct] = __builtin_amdgcn_mfma_f32_16x16x32_f16(a0, w1, acc[1][ct], 0, 0, 0);
            acc[2][ct] = __builtin_amdgcn_mfma_f32_16x16x32_f16(r0f, w2, acc[2][ct], 0, 0, 0);
            if constexpr (sizeof(AT) == 4) {
                acc[0][ct] = __builtin_amdgcn_mfma_f32_16x16x32_f16(a1, w0, acc[0][ct], 0, 0, 0);
                acc[1][ct] = __builtin_amdgcn_mfma_f32_16x16x32_f16(a1, w1, acc[1][ct], 0, 0, 0);
                acc[2][ct] = __builtin_amdgcn_mfma_f32_16x16x32_f16(r1f, w2, acc[2][ct], 0, 0, 0);
            }
        }
    };

    uint4 rA[3][NR];
    loadA(0, rA[0]);
    loadA(1, rA[1]);
    stage(0, 0);
#pragma unroll
    for (int ks = 0; ks < KSTEPS; ++ks) {
        if (ks + 1 < KSTEPS) {
            stage((ks + 1) & 1, ks + 1);
            asm volatile("" ::: "memory");  // pin: stage(ks+1) issues before loadA(ks+2)
        }
        if (ks + 2 < KSTEPS) loadA(ks + 2, rA[(ks + 2) % 3]);
        if (ks == 0 || ks == KSTEPS - 2) vwaitn(NR + 6);
        else if (ks + 2 < KSTEPS) vwaitn(2 * NR + 6);
        else vwaitn(0);
        __builtin_amdgcn_s_barrier();
        compute(rA[ks % 3], &sB[ks & 1][0]);
        __builtin_amdgcn_s_barrier();
    }

    int rb = row0 + kg * 4;
#pragma unroll
    for (int ct = 0; ct < 8; ++ct) {
        int c = ct * 16 + rr;
        float bv = biasf[c];
#pragma unroll
        for (int j = 0; j < 4; ++j) {
            int row = rb + j;
            if (row < N) {
                size_t o = (size_t)row * H + c;
                O0[o] = (_Float16)acc[0][ct][j];
                O1[o] = (_Float16)acc[1][ct][j];
                stT(O2, o, acc[2][ct][j] + bv);
            }
        }
    }
}

// unified gemm kernel: LAYER=0 (A = external dtype, K=256, O2 = hb f16),
// LAYER=1 (A = f16 hb, K=128, O2 = embF f32 / embB bf16 by flag).
template <int LAYER>
__global__ __launch_bounds__(256) void gemm3_u(const int* __restrict__ flag, const void* Aext,
                                               const _Float16* Af16, int N,
                                               const _Float16* __restrict__ Bp,
                                               const float* __restrict__ biasf,
                                               _Float16* __restrict__ O0,
                                               _Float16* __restrict__ O1, _Float16* O2h,
                                               float* O2f, __hip_bfloat16* O2b) {
    __shared__ _Float16 sB[2][12288];  // 48KB
    int f = flag[0];
    if constexpr (LAYER == 0) {
        if (f == 0)
            gemm_body<float, _Float16, 8>((const float*)Aext, N, Bp, biasf, O0, O1, O2h, sB);
        else
            gemm_body<__hip_bfloat16, _Float16, 8>((const __hip_bfloat16*)Aext, N, Bp, biasf,
                                                   O0, O1, O2h, sB);
    } else {
        if (f == 0)
            gemm_body<_Float16, float, 4>(Af16, N, Bp, biasf, O0, O1, O2f, sB);
        else
            gemm_body<_Float16, __hip_bfloat16, 4>(Af16, N, Bp, biasf, O0, O1, O2b, sB);
    }
}

// ---------------------------------------------------------------------------
// GATv2 edge phase body, H=128: 16 lanes per dst node, 8 edges/iteration
// (R10-measured best: 45.8us).
// FINAL=1: fuse the 128->2 final-layer GEMMs into the epilogue.
// ---------------------------------------------------------------------------
template <typename IOT, typename T, int FINAL>
__device__ void gat_body(const _Float16* __restrict__ xs, const _Float16* __restrict__ xd,
                         const int* __restrict__ rowptr, const int* __restrict__ csr_src,
                         IOT* __restrict__ io, const T* __restrict__ att,
                         const T* __restrict__ gbias, int n, int relu_out,
                         const T* __restrict__ Wl, const T* __restrict__ Wr,
                         const T* __restrict__ Wres, const T* __restrict__ bres,
                         float* __restrict__ xsf, float* __restrict__ xdf,
                         float* __restrict__ resf) {
    int tid = threadIdx.x;
    int l = tid & 15;   // feature lane: feats l*8 .. l*8+7
    int g = tid >> 4;   // group (node) in block
    int dst = blockIdx.x * 16 + g;
    if (blockIdx.x * 16 + ((tid >> 6) << 2) >= n) return;  // whole wave OOB
    int dstc = min(dst, n - 1);
    bool act = dst < n;

    union U4H { uint4 u; h2v h[4]; };
    U4H du; du.u = *(const uint4*)(xd + (size_t)dstc * 128 + l * 8);
    h2v ap[4];
#pragma unroll
    for (int c = 0; c < 4; ++c) {
        ap[c][0] = (_Float16)toF(att[l * 8 + 2 * c]);
        ap[c][1] = (_Float16)toF(att[l * 8 + 2 * c + 1]);
    }
    const _Float16 ks = (_Float16)NEG_SLOPE;
    const h2v k02 = {ks, ks};

    int beg = rowptr[dstc];
    int end = act ? rowptr[dstc + 1] : beg;
    float m = -INFINITY, s = 0.f;
    h2v acc[4];
#pragma unroll
    for (int c = 0; c < 4; ++c) acc[c] = h2v{(_Float16)0.f, (_Float16)0.f};

    for (int j = beg; j < end; j += 8) {
        int rem = end - j;
        U4H v[8];
#pragma unroll
        for (int q = 0; q < 8; ++q) {
            int idx = j + ((rem > q) ? q : 0);
            int sq = csr_src[idx];
            v[q].u = *(const uint4*)(xs + (size_t)sq * 128 + l * 8);
        }
        float p[8];
#pragma unroll
        for (int q = 0; q < 8; ++q) p[q] = 0.f;
#pragma unroll
        for (int c = 0; c < 4; ++c) {
#pragma unroll
            for (int q = 0; q < 8; ++q) {
                h2v t = v[q].h[c] + du.h[c];
                t = __builtin_elementwise_max(t, t * k02);  // leaky: max(h, 0.2h)
                p[q] = __builtin_amdgcn_fdot2(t, ap[c], p[q], false);
            }
        }
#pragma unroll
        for (int o = 1; o < 16; o <<= 1) {
#pragma unroll
            for (int q = 0; q < 8; ++q) p[q] += __shfl_xor(p[q], o, 16);
        }
#pragma unroll
        for (int q = 1; q < 8; ++q)
            if (rem < q + 1) p[q] = -INFINITY;
        float pm = p[0];
#pragma unroll
        for (int q = 1; q < 8; ++q) pm = fmaxf(pm, p[q]);
        float nm = fmaxf(m, pm);
        float sc = __expf(m - nm);  // first iter: exp(-inf)=0
        float w[8];
        float ws = 0.f;
#pragma unroll
        for (int q = 0; q < 8; ++q) {
            w[q] = __expf(p[q] - nm);
            ws += w[q];
        }
        s = s * sc + ws;
        _Float16 sch = (_Float16)sc;
        h2v scp = {sch, sch};
        h2v wp[8];
#pragma unroll
        for (int q = 0; q < 8; ++q) {
            _Float16 wh = (_Float16)w[q];
            wp[q] = h2v{wh, wh};
        }
#pragma unroll
        for (int c = 0; c < 4; ++c) {
            h2v a = acc[c] * scp;
#pragma unroll
            for (int q = 0; q < 8; ++q) a = a + v[q].h[c] * wp[q];
            acc[c] = a;
        }
        m = nm;
    }

    if (act) {
        float r = 1.f / (s + 1e-16f);
        size_t base = (size_t)dst * 128 + l * 8;
        float ev[8];
#pragma unroll
        for (int c = 0; c < 4; ++c) {
            int f0 = l * 8 + 2 * c;
            float v0 = (float)acc[c][0] * r + toF(gbias[f0]) + toF(io[base + 2 * c]);
            float v1 = (float)acc[c][1] * r + toF(gbias[f0 + 1]) + toF(io[base + 2 * c + 1]);
            if (relu_out) { v0 = fmaxf(v0, 0.f); v1 = fmaxf(v1, 0.f); }
            stT(io, base + 2 * c, v0);
            stT(io, base + 2 * c + 1, v1);
            ev[2 * c] = v0;
            ev[2 * c + 1] = v1;
        }
        if constexpr (FINAL) {
            float d[6] = {0.f, 0.f, 0.f, 0.f, 0.f, 0.f};
#pragma unroll
            for (int f = 0; f < 8; ++f) {
                int fg = (l * 8 + f) * 2;
                float e = ev[f];
                float rp = fmaxf(e, 0.f);
                d[0] += e * toF(Wl[fg]);
                d[1] += e * toF(Wl[fg + 1]);
                d[2] += e * toF(Wr[fg]);
                d[3] += e * toF(Wr[fg + 1]);
                d[4] += rp * toF(Wres[fg]);
                d[5] += rp * toF(Wres[fg + 1]);
            }
#pragma unroll
            for (int i = 0; i < 6; ++i) {
#pragma unroll
                for (int o = 1; o < 16; o <<= 1) d[i] += __shfl_xor(d[i], o, 16);
            }
            if (l == 0) {
                xsf[dst * 2 + 0] = d[0];
                xsf[dst * 2 + 1] = d[1];
                xdf[dst * 2 + 0] = d[2];
                xdf[dst * 2 + 1] = d[3];
                resf[dst * 2 + 0] = d[4] + toF(bres[0]);
                resf[dst * 2 + 1] = d[5] + toF(bres[1]);
            }
        }
    }
}

// unified gat kernel: FINAL=0 (io = hb f16), FINAL=1 (io = embF/embB by flag,
// fused final-layer 128->2 GEMMs).
template <int FINAL>
__global__ __launch_bounds__(256) void gat_u(const int* __restrict__ flag,
                                             const _Float16* __restrict__ xs,
                                             const _Float16* __restrict__ xd,
                                             const int* __restrict__ rowptr,
                                             const int* __restrict__ csr_src, _Float16* io_h,
                                             float* io_f, __hip_bfloat16* io_b, const void* att,
                                             const void* gbias, int n, int relu_out,
                                             const void* Wl, const void* Wr, const void* Wres,
                                             const void* bres, float* xsf, float* xdf,
                                             float* resf) {
    typedef __hip_bfloat16 bf;
    int f = flag[0];
    if constexpr (FINAL == 0) {
        if (f == 0)
            gat_body<_Float16, float, 0>(xs, xd, rowptr, csr_src, io_h, (const float*)att,
                                         (const float*)gbias, n, relu_out, nullptr, nullptr,
                                         nullptr, nullptr, nullptr, nullptr, nullptr);
        else
            gat_body<_Float16, bf, 0>(xs, xd, rowptr, csr_src, io_h, (const bf*)att,
                                      (const bf*)gbias, n, relu_out, nullptr, nullptr, nullptr,
                                      nullptr, nullptr, nullptr, nullptr);
    } else {
        if (f == 0)
            gat_body<float, float, 1>(xs, xd, rowptr, csr_src, io_f, (const float*)att,
                                      (const float*)gbias, n, relu_out, (const float*)Wl,
                                      (const float*)Wr, (const float*)Wres, (const float*)bres,
                                      xsf, xdf, resf);
        else
            gat_body<bf, bf, 1>(xs, xd, rowptr, csr_src, io_b, (const bf*)att, (const bf*)gbias,
                                n, relu_out, (const bf*)Wl, (const bf*)Wr, (const bf*)Wres,
                                (const bf*)bres, xsf, xdf, resf);
    }
}

// ---------------------------------------------------------------------------
// Final edge phase (OUT=2): one thread per dst node, 4-way unrolled online
// softmax.
// ---------------------------------------------------------------------------
template <typename T>
__device__ void fe_body(const float* __restrict__ xsf, const float* __restrict__ xdf,
                        const float* __restrict__ resf, const int* __restrict__ rowptr,
                        const int* __restrict__ csr_src, const T* __restrict__ att,
                        const T* __restrict__ gb, T* __restrict__ out, int n) {
    int dst = blockIdx.x * blockDim.x + threadIdx.x;
    if (dst >= n) return;
    float2 dv = ((const float2*)xdf)[dst];
    float a0 = toF(att[0]), a1 = toF(att[1]);
    float m = -INFINITY, s = 0.f, acc0 = 0.f, acc1 = 0.f;
    int beg = rowptr[dst], end = rowptr[dst + 1];
    for (int j = beg; j < end; j += 4) {
        int rem = end - j;
        int i1 = (rem > 1) ? 1 : 0, i2 = (rem > 2) ? 2 : 0, i3 = (rem > 3) ? 3 : 0;
        int s0 = csr_src[j];
        int s1 = csr_src[j + i1];
        int s2 = csr_src[j + i2];
        int s3 = csr_src[j + i3];
        float2 v0 = ((const float2*)xsf)[s0];
        float2 v1 = ((const float2*)xsf)[s1];
        float2 v2 = ((const float2*)xsf)[s2];
        float2 v3 = ((const float2*)xsf)[s3];
        float h0, h1, e0, e1, e2, e3;
        h0 = v0.x + dv.x; h0 = fmaxf(h0, NEG_SLOPE * h0);
        h1 = v0.y + dv.y; h1 = fmaxf(h1, NEG_SLOPE * h1);
        e0 = h0 * a0 + h1 * a1;
        h0 = v1.x + dv.x; h0 = fmaxf(h0, NEG_SLOPE * h0);
        h1 = v1.y + dv.y; h1 = fmaxf(h1, NEG_SLOPE * h1);
        e1 = h0 * a0 + h1 * a1;
        h0 = v2.x + dv.x; h0 = fmaxf(h0, NEG_SLOPE * h0);
        h1 = v2.y + dv.y; h1 = fmaxf(h1, NEG_SLOPE * h1);
        e2 = h0 * a0 + h1 * a1;
        h0 = v3.x + dv.x; h0 = fmaxf(h0, NEG_SLOPE * h0);
        h1 = v3.y + dv.y; h1 = fmaxf(h1, NEG_SLOPE * h1);
        e3 = h0 * a0 + h1 * a1;
        if (rem < 2) e1 = -INFINITY;
        if (rem < 3) e2 = -INFINITY;
        if (rem < 4) e3 = -INFINITY;
        float pm = fmaxf(fmaxf(e0, e1), fmaxf(e2, e3));
        float nm = fmaxf(m, pm);
        float sc = __expf(m - nm);
        float w0 = __expf(e0 - nm), w1 = __expf(e1 - nm);
        float w2 = __expf(e2 - nm), w3 = __expf(e3 - nm);
        s = s * sc + ((w0 + w1) + (w2 + w3));
        acc0 = acc0 * sc + ((w0 * v0.x + w1 * v1.x) + (w2 * v2.x + w3 * v3.x));
        acc1 = acc1 * sc + ((w0 * v0.y + w1 * v1.y) + (w2 * v2.y + w3 * v3.y));
        m = nm;
    }
    float r = 1.f / (s + 1e-16f);
    float2 rv = ((const float2*)resf)[dst];
    stT(out, (size_t)dst * 2 + 0, acc0 * r + toF(gb[0]) + rv.x);
    stT(out, (size_t)dst * 2 + 1, acc1 * r + toF(gb[1]) + rv.y);
}

__global__ void final_edge_u(const int* __restrict__ flag, const float* __restrict__ xsf,
                             const float* __restrict__ xdf, const float* __restrict__ resf,
                             const int* __restrict__ rowptr, const int* __restrict__ csr_src,
                             const void* att, const void* gb, void* out, int n) {
    typedef __hip_bfloat16 bf;
    if (flag[0] == 0)
        fe_body<float>(xsf, xdf, resf, rowptr, csr_src, (const float*)att, (const float*)gb,
                       (float*)out, n);
    else
        fe_body<bf>(xsf, xdf, resf, rowptr, csr_src, (const bf*)att, (const bf*)gb, (bf*)out, n);
}

// ---------------------------------------------------------------------------
extern "C" void kernel_launch(void* const* d_in, const int* in_sizes, int n_in,
                              void* d_out, int out_size, void* d_ws, size_t ws_size,
                              hipStream_t stream) {
    typedef __hip_bfloat16 bf;
    typedef _Float16 f16;
    const int IN = 256, H = 128;
    const int N = in_sizes[0] / IN;  // 50000
    const int E = in_sizes[1] / 2;   // 800000

    const int* ei = (const int*)d_in[1];

    size_t off = 0;
    auto alloc = [&](size_t bytes) {
        void* p = (char*)d_ws + off;
        off += (bytes + 255) & ~(size_t)255;
        return p;
    };
    f16* xs = (f16*)alloc((size_t)N * H * 2);
    f16* xd = (f16*)alloc((size_t)N * H * 2);
    f16* hb = (f16*)alloc((size_t)N * H * 2);
    int* flag = (int*)alloc(256);
    int* rowptr = (int*)alloc((size_t)(N + 1) * 4);
    int* fill = (int*)alloc((size_t)N * 4);
    int* blksum = (int*)alloc(256 * 4);
    int* csr_src = (int*)alloc((size_t)E * 4);
    float* xsf = (float*)alloc((size_t)N * 2 * 4);
    float* xdf = (float*)alloc((size_t)N * 2 * 4);
    float* resf = (float*)alloc((size_t)N * 2 * 4);
    f16* Bp0 = (f16*)alloc((size_t)3 * 8 * 8 * 512 * 2);  // 192 KB, ks-major
    f16* Bp1 = (f16*)alloc((size_t)3 * 4 * 8 * 512 * 2);  // 96 KB
    float* bias0 = (float*)alloc(128 * 4);
    float* bias1 = (float*)alloc(128 * 4);
    // bucketed CSR build buffers (coarse buckets of 1024 dst nodes)
    const int NB = (N + 1023) / 1024;              // <= 64 when N <= 65536
    const int CAP = ((2 * (E / (NB > 0 ? NB : 1) + 1) + 255) / 256) * 256;  // 2x mean
    int* gcnt = (int*)alloc(64 * 4);
    unsigned* bbuf = (unsigned*)alloc((size_t)NB * CAP * 4);

    const int* e_src = ei;
    const int* e_dst = ei + E;

    // ---- prep: detect + zero gcnt + pack both weight sets (1 launch) ----
    k_prep<<<1 + 193 + 97, 64, 0, stream>>>((const unsigned*)d_in[0], flag, gcnt,
                                            d_in[2], d_in[3], d_in[14], d_in[15],
                                            d_in[6], d_in[7], d_in[16], d_in[17],
                                            Bp0, bias0, Bp1, bias1);

    const int g64 = (N + 63) / 64;     // MFMA gemm grid: 64 rows/block
    const int eblk16 = (N + 15) / 16;  // gat grid: 16 nodes/block
    const int ncnt = (E + 4095) / 4096;

    float* embF = (float*)d_out + (size_t)N * 2;
    bf* embB = (bf*)d_out + (size_t)N * 2;

    // ---- CSR build ----
    if (N <= 65536) {  // bucketed path (src fits 16 bits, dst-local 10 bits)
        k_cnt<<<ncnt, 256, 0, stream>>>(e_src, e_dst, E, gcnt, bbuf, CAP);
        k_bhp<<<NB, 256, 0, stream>>>(gcnt, bbuf, CAP, rowptr, csr_src, N, NB);
    } else {  // legacy fallback
        const int nblk = (N + 1023) / 1024;
        hipMemsetAsync(rowptr, 0, (size_t)(N + 1) * 4, stream);
        hipMemsetAsync(fill, 0, (size_t)N * 4, stream);
        k_hist<<<(E + 255) / 256, 256, 0, stream>>>(e_dst, E, rowptr);
        k_scan1<<<nblk, 256, 0, stream>>>(rowptr, blksum, N);
        k_scan2<<<1, 64, 0, stream>>>(blksum, nblk);
        k_scan3<<<(N + 255) / 256, 256, 0, stream>>>(rowptr, blksum, N);
        k_scatter<<<(E + 255) / 256, 256, 0, stream>>>(e_src, e_dst, E, rowptr, fill, csr_src);
    }

    // ---- layer 0: x[N,256] -> xs/xd/hb (f16 internals) ----
    gemm3_u<0><<<g64, 256, 0, stream>>>(flag, d_in[0], nullptr, N, Bp0, bias0, xs, xd, hb,
                                        nullptr, nullptr);
    gat_u<0><<<eblk16, 256, 0, stream>>>(flag, xs, xd, rowptr, csr_src, hb, nullptr, nullptr,
                                         d_in[4], d_in[5], N, 1, nullptr, nullptr, nullptr,
                                         nullptr, nullptr, nullptr, nullptr);

    // ---- layer 1: hb[N,128] -> emb in d_out + fused final-layer GEMMs ----
    gemm3_u<1><<<g64, 256, 0, stream>>>(flag, nullptr, hb, N, Bp1, bias1, xs, xd, nullptr,
                                        embF, embB);
    gat_u<1><<<eblk16, 256, 0, stream>>>(flag, xs, xd, rowptr, csr_src, nullptr, embF, embB,
                                         d_in[8], d_in[9], N, 0, d_in[10], d_in[11], d_in[18],
                                         d_in[19], xsf, xdf, resf);

    // ---- final edge phase: xsf/xdf/resf -> out [N,2] ----
    final_edge_u<<<(N + 255) / 256, 256, 0, stream>>>(flag, xsf, xdf, resf, rowptr, csr_src,
                                                      d_in[12], d_in[13], d_out, N);
}